// Round 4
// baseline (457.221 us; speedup 1.0000x reference)
//
#include <hip/hip_runtime.h>

#define B_  2
#define S_  2048
#define E_  2048
#define H_  16
#define D_  128
#define BS_ (B_*S_)

typedef __bf16 bf16_t;
typedef __bf16 bf16x8 __attribute__((ext_vector_type(8)));
typedef __bf16 bf16x4 __attribute__((ext_vector_type(4)));
typedef float  f32x4  __attribute__((ext_vector_type(4)));
typedef float  f32x16 __attribute__((ext_vector_type(16)));

// combined softmax scale: 1/sqrt(128) * log2(e), folded into Q projection
#define QSCALE 0.1275174131003543f

// ---------------- async global->LDS, 16B per lane per call ----------------
__device__ __forceinline__ void gld16(const bf16_t* g, bf16_t* l) {
    __builtin_amdgcn_global_load_lds(
        (const __attribute__((address_space(1))) void*)g,
        (__attribute__((address_space(3))) void*)l,
        16, 0, 0);
}

// ---------------- fused fp32 -> bf16 convert (x, kv, 4 weights) ----------------
__global__ void cvt_all(const float* __restrict__ s0, const float* __restrict__ s1,
                        const float* __restrict__ s2, const float* __restrict__ s3,
                        const float* __restrict__ s4, const float* __restrict__ s5,
                        bf16_t* d0, bf16_t* d1, bf16_t* d2,
                        bf16_t* d3, bf16_t* d4, bf16_t* d5)
{
    long i = ((long)blockIdx.x * blockDim.x + threadIdx.x) * 4;
    const float* s; bf16_t* d;
    if      (i <  8388608) { s = s0; d = d0; }
    else if (i < 16777216) { s = s1; d = d1; i -=  8388608; }
    else if (i < 20971520) { s = s2; d = d2; i -= 16777216; }
    else if (i < 21233664) { s = s3; d = d3; i -= 20971520; }
    else if (i < 21495808) { s = s4; d = d4; i -= 21233664; }
    else                   { s = s5; d = d5; i -= 21495808; }
    float4 v = *(const float4*)(s + i);
    bf16x4 o;
    o[0] = (bf16_t)v.x; o[1] = (bf16_t)v.y; o[2] = (bf16_t)v.z; o[3] = (bf16_t)v.w;
    *(bf16x4*)(d + i) = o;
}

// ========== GEMM tile core: 128x64 tile, single-buffer gld16 K-loop ==========
template<int EP>
__device__ __forceinline__ void gemm_tile64(
    const bf16_t* __restrict__ A, const bf16_t* __restrict__ W,
    const float* __restrict__ biasA, const float* __restrict__ biasB,
    float* __restrict__ Cf, bf16_t* __restrict__ Cb,
    int N, int K, float scale, int m0, int w_n0, int c_n0,
    bf16_t* As, bf16_t* Bs)
{
    const int tid  = threadIdx.x;
    const int wave = tid >> 6, lane = tid & 63;
    const int wm = wave >> 1, wn = wave & 1;
    const int lrow = lane & 15, quad = lane >> 4;
    const int r8 = lane >> 3, c8 = (lane & 7) << 3;

    f32x4 acc[4][2] = {};

    for (int k0 = 0; k0 < K; k0 += 64) {
        __syncthreads();
#pragma unroll
        for (int j = 0; j < 4; ++j) {
            int base = (wave * 4 + j) * 8;
            gld16(A + (size_t)(m0 + base + r8) * K + k0 + c8, &As[base * 64]);
        }
#pragma unroll
        for (int j = 0; j < 2; ++j) {
            int base = (wave * 2 + j) * 8;
            gld16(W + (size_t)(w_n0 + base + r8) * K + k0 + c8, &Bs[base * 64]);
        }
        __syncthreads();
#pragma unroll
        for (int ks = 0; ks < 2; ++ks) {
            bf16x8 af[4], bfr[2];
#pragma unroll
            for (int mt = 0; mt < 4; ++mt)
                af[mt] = *(const bf16x8*)&As[(wm * 64 + mt * 16 + lrow) * 64 + ks * 32 + quad * 8];
#pragma unroll
            for (int nt = 0; nt < 2; ++nt)
                bfr[nt] = *(const bf16x8*)&Bs[(wn * 32 + nt * 16 + lrow) * 64 + ks * 32 + quad * 8];
#pragma unroll
            for (int mt = 0; mt < 4; ++mt)
#pragma unroll
                for (int nt = 0; nt < 2; ++nt)
                    acc[mt][nt] = __builtin_amdgcn_mfma_f32_16x16x32_bf16(
                        af[mt], bfr[nt], acc[mt][nt], 0, 0, 0);
        }
    }

#pragma unroll
    for (int mt = 0; mt < 4; ++mt) {
#pragma unroll
        for (int nt = 0; nt < 2; ++nt) {
            int nn = wn * 32 + nt * 16 + lrow;
            int col = c_n0 + nn;
            float bvv = (EP == 1 && biasB && col >= 128) ? biasB[col - 128]
                                                         : biasA[col];
#pragma unroll
            for (int r = 0; r < 4; ++r) {
                int row = m0 + wm * 64 + mt * 16 + quad * 4 + r;
                float v = (acc[mt][nt][r] + bvv) * scale;
                if (EP == 0) Cf[(size_t)row * N + col] = v;
                else         Cb[(size_t)row * N + col] = (bf16_t)v;
            }
        }
    }
}

// ---------------- fused Q + K + V projection ----------------
__global__ __launch_bounds__(256) void gemm_qkv(
    const bf16_t* __restrict__ xb, const bf16_t* __restrict__ kvb,
    const bf16_t* __restrict__ Wq, const bf16_t* __restrict__ Wkv,
    const float* __restrict__ bq, const float* __restrict__ bk,
    const float* __restrict__ bv,
    bf16_t* __restrict__ Qb, bf16_t* __restrict__ KVb)
{
    __shared__ __align__(16) bf16_t As[128 * 64];
    __shared__ __align__(16) bf16_t Bs[64 * 64];
    const int m0 = blockIdx.y * 128;
    if (blockIdx.x < 32) {
        int n0 = blockIdx.x * 64;
        gemm_tile64<1>(xb, Wq, bq, nullptr, nullptr, Qb, E_, E_, QSCALE,
                       m0, n0, n0, As, Bs);
    } else {
        int n0 = (blockIdx.x - 32) * 64;
        gemm_tile64<1>(kvb, Wkv, bk, bv, nullptr, KVb, 256, E_, 1.0f,
                       m0, n0, n0, As, Bs);
    }
}

// ---------------- O projection (fp32 out, direct store) ----------------
__global__ __launch_bounds__(256) void gemm_o(
    const bf16_t* __restrict__ A, const bf16_t* __restrict__ W,
    const float* __restrict__ bias, float* __restrict__ Cf)
{
    __shared__ __align__(16) bf16_t As[128 * 64];
    __shared__ __align__(16) bf16_t Bs[64 * 64];
    int n0 = blockIdx.x * 64;
    gemm_tile64<0>(A, W, bias, nullptr, Cf, nullptr, E_, E_, 1.0f,
                   blockIdx.y * 128, n0, n0, As, Bs);
}

// ---------------- flash-style causal MQA attention ----------------
// 8 waves = 4 q-waves x 2 key-parity waves. Each q-wave pair covers 32 q-rows;
// parity wave wk computes key-tiles kt (kt&1==wk) of the 128-key staging period
// -> 16 waves/CU (4/SIMD) with halved per-wave serial chain. Partials (oacc,rs)
// merged once via LDS at the end.
// K staged via global_load_lds with XOR-swizzled SOURCE (linear LDS dest) and
// matching swizzled ds_read (rule #21); V reg-staged transposed (paired b32).
// Q pre-scaled bf16 [B,S,H,D]; KV interleaved bf16 [B,S,128K|128V]; O bf16.
__global__ __launch_bounds__(512, 4) void mqa_attn(
    const bf16_t* __restrict__ Q, const bf16_t* __restrict__ KV,
    bf16_t* __restrict__ O)
{
    __shared__ __align__(16) unsigned char SMEM[68608];
    bf16_t* Ks = (bf16_t*)SMEM;                          // [128][128] swizzled, 32 KB
    bf16_t (*Vt)[136] = (bf16_t(*)[136])(SMEM + 32768);  // [d=128][k=128 +pad8], 34816 B
    float* rsl = (float*)(SMEM + 67584);                 // [8][32]
    float* mrg = (float*)SMEM;                           // 64 KB overlay for oacc merge

    const int bx = blockIdx.x, h = blockIdx.y, b = blockIdx.z;
    const int qb = b ? bx : (15 - bx);                   // complementary pairing
    const int tid = threadIdx.x, wave = tid >> 6, lane = tid & 63;
    const int wq = wave >> 1, wk = wave & 1;
    const int ln = lane & 31, hi = lane >> 5;
    const int q0w = qb * 128 + wq * 32;

    const bf16_t* kvp = KV + (size_t)(b * S_) * 256;

    // Q fragments (B-operand): lane holds Q[q0w+ln][st*16 + hi*8 + j]
    bf16x8 qf[8];
    {
        const bf16_t* qp = Q + ((size_t)(b * S_ + q0w + ln)) * E_ + h * D_ + hi * 8;
#pragma unroll
        for (int st = 0; st < 8; ++st) qf[st] = *(const bf16x8*)(qp + st * 16);
    }

    f32x16 oacc[4] = {};
    float rs = 0.f;

    const int nper = qb + 1;   // periods of 128 keys (= 2 tiles of 64)

    // V prefetch regs: thread covers keys {2c&127, +1} x 8 dims at d0=8*(c>>6)
    bf16x8 vA[2], vB[2];
    auto loadV = [&](int k0) {
#pragma unroll
        for (int i = 0; i < 2; ++i) {
            int c = tid + 512 * i;
            int n = (c & 63) * 2, d0 = (c >> 6) << 3;
            const bf16_t* src = kvp + (size_t)(k0 + n) * 256 + 128 + d0;
            vA[i] = *(const bf16x8*)src;
            vB[i] = *(const bf16x8*)(src + 256);
        }
    };
    loadV(0);

    for (int p = 0; p < nper; ++p) {
        const int k0 = p * 128;
        __syncthreads();                       // (a) prev compute done, LDS free
        // ---- V staging: transposed, paired-key b32 writes ----
#pragma unroll
        for (int i = 0; i < 2; ++i) {
            int c = tid + 512 * i;
            int n = (c & 63) * 2, d0 = (c >> 6) << 3;
#pragma unroll
            for (int j = 0; j < 8; ++j) {
                union { bf16_t h[2]; unsigned u; } w2;
                w2.h[0] = vA[i][j]; w2.h[1] = vB[i][j];
                *(unsigned*)&Vt[d0 + j][n] = w2.u;
            }
        }
        // ---- K staging: gld16 with pre-swizzled global source ----
        // physical unit c stores logical unit c ^ (row&7) (16B units)
#pragma unroll
        for (int j = 0; j < 4; ++j) {
            int r = (wave * 4 + j) * 4 + (lane >> 4);
            int cl = (lane & 15) ^ (r & 7);
            gld16(kvp + (size_t)(k0 + r) * 256 + cl * 8, Ks + (wave * 4 + j) * 512);
        }
        asm volatile("s_waitcnt vmcnt(0)" ::: "memory");
        __syncthreads();                       // (b) staging visible
        if (p + 1 < nper) loadV(k0 + 128);     // V prefetch overlaps compute

        const int kt = 2 * p + wk;
        const int k_base = kt * 64;
        if (k_base <= q0w + 31) {              // wave-uniform causal skip
            const int x8 = ln & 7;
            // -------- swapped QK^T: sc[ct] = S^T[k][q=ln], swizzled K reads ----
            f32x16 sc[2] = {f32x16{}, f32x16{}};
            __builtin_amdgcn_s_setprio(1);
#pragma unroll
            for (int st = 0; st < 8; ++st) {
                bf16x8 qv = qf[st];
#pragma unroll
                for (int ct = 0; ct < 2; ++ct) {
                    const bf16_t* kb = Ks + (wk * 64 + ct * 32 + ln) * 128
                                          + ((((st << 1) | hi) ^ x8) << 3);
                    sc[ct] = __builtin_amdgcn_mfma_f32_32x32x16_bf16(
                        *(const bf16x8*)kb, qv, sc[ct], 0, 0, 0);
                }
            }
            __builtin_amdgcn_s_setprio(0);
            // -------- mask + exp2 softmax (log2-domain, no clamp needed) ------
            const int qi = q0w + ln;
            const bool diag = (k_base + 63 > q0w);
#pragma unroll
            for (int ct = 0; ct < 2; ++ct) {
#pragma unroll
                for (int r = 0; r < 16; ++r) {
                    float s = sc[ct][r];
                    if (diag) {
                        int kj = k_base + ct * 32 + (r & 3) + 8 * (r >> 2) + 4 * hi;
                        if (kj > qi) s = -1e30f;
                    }
                    float pv = exp2f(s);
                    rs += pv;
                    sc[ct][r] = pv;
                }
            }
            // -------- P -> A-frags in-register (cvt_pk casts + shfl_xor 32) ---
            bf16x8 af[4];
#pragma unroll
            for (int ks = 0; ks < 4; ++ks) {
                const int c = ks >> 1, b8 = (ks & 1) * 8;
                union { bf16_t h[2]; unsigned u; } pk0, pk1, pk2, pk3;
                pk0.h[0] = (bf16_t)sc[c][b8 + 0]; pk0.h[1] = (bf16_t)sc[c][b8 + 1];
                pk1.h[0] = (bf16_t)sc[c][b8 + 2]; pk1.h[1] = (bf16_t)sc[c][b8 + 3];
                pk2.h[0] = (bf16_t)sc[c][b8 + 4]; pk2.h[1] = (bf16_t)sc[c][b8 + 5];
                pk3.h[0] = (bf16_t)sc[c][b8 + 6]; pk3.h[1] = (bf16_t)sc[c][b8 + 7];
                const unsigned U0 = pk0.u, U1 = pk1.u, U2 = pk2.u, U3 = pk3.u;
                const unsigned V0 = __shfl_xor(U0, 32);
                const unsigned V1 = __shfl_xor(U1, 32);
                const unsigned V2 = __shfl_xor(U2, 32);
                const unsigned V3 = __shfl_xor(U3, 32);
                union { unsigned u[4]; bf16x8 v; } W;
                W.u[0] = hi ? V2 : U0;
                W.u[1] = hi ? V3 : U1;
                W.u[2] = hi ? U2 : V0;
                W.u[3] = hi ? U3 : V1;
                af[ks] = W.v;
            }
            // -------- PV: oacc[t] += P * V (B-frag from transposed Vt) --------
            __builtin_amdgcn_s_setprio(1);
#pragma unroll
            for (int ks = 0; ks < 4; ++ks)
#pragma unroll
                for (int t = 0; t < 4; ++t) {
                    bf16x8 vf = *(const bf16x8*)&Vt[t * 32 + ln][wk * 64 + ks * 16 + hi * 8];
                    oacc[t] = __builtin_amdgcn_mfma_f32_32x32x16_bf16(af[ks], vf, oacc[t], 0, 0, 0);
                }
            __builtin_amdgcn_s_setprio(0);
        }
    }

    // -------- epilogue: merge parity partials via LDS, normalize, store ------
    __syncthreads();                           // compute done; LDS reusable
    rs += __shfl_xor(rs, 32);
    if (lane < 32) rsl[wave * 32 + ln] = rs;
    if (wk) {
#pragma unroll
        for (int t = 0; t < 4; ++t) {
            union { f32x16 v; f32x4 q[4]; } u; u.v = oacc[t];
            float* d = mrg + (size_t)(((wq << 2) + t) * 64 + lane) * 16;
#pragma unroll
            for (int r4 = 0; r4 < 4; ++r4) *(f32x4*)(d + r4 * 4) = u.q[r4];
        }
    }
    __syncthreads();
    if (!wk) {
        float inv[16];
#pragma unroll
        for (int r = 0; r < 16; ++r) {
            int ro = (r & 3) + 8 * (r >> 2) + 4 * hi;
            inv[r] = 1.0f / (rsl[(wq * 2) * 32 + ro] + rsl[(wq * 2 + 1) * 32 + ro]);
        }
#pragma unroll
        for (int t = 0; t < 4; ++t) {
            union { f32x16 v; f32x4 q[4]; } u; u.v = oacc[t];
            const float* d = mrg + (size_t)(((wq << 2) + t) * 64 + lane) * 16;
#pragma unroll
            for (int r4 = 0; r4 < 4; ++r4) {
                f32x4 m = *(const f32x4*)(d + r4 * 4);
                u.q[r4] += m;
            }
#pragma unroll
            for (int r = 0; r < 16; ++r) {
                int ro = (r & 3) + 8 * (r >> 2) + 4 * hi;
                O[((size_t)(b * S_ + q0w + ro)) * E_ + h * D_ + t * 32 + ln] =
                    (bf16_t)(u.v[r] * inv[r]);
            }
        }
    }
}

// ---------------- launch ----------------
extern "C" void kernel_launch(void* const* d_in, const int* in_sizes, int n_in,
                              void* d_out, int out_size, void* d_ws, size_t ws_size,
                              hipStream_t stream)
{
    const float* x   = (const float*)d_in[0];
    const float* kv  = (const float*)d_in[1];
    const float* Wq  = (const float*)d_in[2];
    const float* bq  = (const float*)d_in[3];
    const float* Wk  = (const float*)d_in[4];
    const float* bk  = (const float*)d_in[5];
    const float* Wv  = (const float*)d_in[6];
    const float* bv  = (const float*)d_in[7];
    const float* Wo  = (const float*)d_in[8];
    const float* bo  = (const float*)d_in[9];
    float* out = (float*)d_out;

    bf16_t* p    = (bf16_t*)d_ws;
    bf16_t* xb   = p;  p += (size_t)BS_ * E_;
    bf16_t* kvb  = p;  p += (size_t)BS_ * E_;
    bf16_t* Wqb  = p;  p += (size_t)E_ * E_;
    bf16_t* Wkvb = p;  p += (size_t)2 * D_ * E_;
    bf16_t* Wob  = p;  p += (size_t)E_ * E_;
    bf16_t* Qb   = p;  p += (size_t)BS_ * E_;
    bf16_t* KVb  = p;  p += (size_t)BS_ * 256;
    bf16_t* Ob   = p;  p += (size_t)BS_ * E_;

    cvt_all<<<dim3(25088), dim3(256), 0, stream>>>(
        x, kv, Wq, Wk, Wv, Wo,
        xb, kvb, Wqb, Wkvb, Wkvb + (size_t)D_ * E_, Wob);

    gemm_qkv<<<dim3(36, BS_ / 128), 256, 0, stream>>>(
        xb, kvb, Wqb, Wkvb, bq, bk, bv, Qb, KVb);

    mqa_attn<<<dim3(S_ / 128, H_, B_), 512, 0, stream>>>(Qb, KVb, Ob);

    gemm_o<<<dim3(E_ / 64, BS_ / 128), 256, 0, stream>>>(Ob, Wob, bo, out);
}

// Round 5
// 387.572 us; speedup vs baseline: 1.1797x; 1.1797x over previous
//
#include <hip/hip_runtime.h>

#define B_  2
#define S_  2048
#define E_  2048
#define H_  16
#define D_  128
#define BS_ (B_*S_)

typedef __bf16 bf16_t;
typedef __bf16 bf16x8 __attribute__((ext_vector_type(8)));
typedef __bf16 bf16x4 __attribute__((ext_vector_type(4)));
typedef float  f32x4  __attribute__((ext_vector_type(4)));
typedef float  f32x16 __attribute__((ext_vector_type(16)));

// combined softmax scale: 1/sqrt(128) * log2(e), folded into Q projection
#define QSCALE 0.1275174131003543f

// ---------------- async global->LDS, 16B per lane per call ----------------
__device__ __forceinline__ void gld16(const bf16_t* g, bf16_t* l) {
    __builtin_amdgcn_global_load_lds(
        (const __attribute__((address_space(1))) void*)g,
        (__attribute__((address_space(3))) void*)l,
        16, 0, 0);
}

// ---------------- fused fp32 -> bf16 convert (x, kv, 4 weights) ----------------
__global__ void cvt_all(const float* __restrict__ s0, const float* __restrict__ s1,
                        const float* __restrict__ s2, const float* __restrict__ s3,
                        const float* __restrict__ s4, const float* __restrict__ s5,
                        bf16_t* d0, bf16_t* d1, bf16_t* d2,
                        bf16_t* d3, bf16_t* d4, bf16_t* d5)
{
    long i = ((long)blockIdx.x * blockDim.x + threadIdx.x) * 4;
    const float* s; bf16_t* d;
    if      (i <  8388608) { s = s0; d = d0; }
    else if (i < 16777216) { s = s1; d = d1; i -=  8388608; }
    else if (i < 20971520) { s = s2; d = d2; i -= 16777216; }
    else if (i < 21233664) { s = s3; d = d3; i -= 20971520; }
    else if (i < 21495808) { s = s4; d = d4; i -= 21233664; }
    else                   { s = s5; d = d5; i -= 21495808; }
    float4 v = *(const float4*)(s + i);
    bf16x4 o;
    o[0] = (bf16_t)v.x; o[1] = (bf16_t)v.y; o[2] = (bf16_t)v.z; o[3] = (bf16_t)v.w;
    *(bf16x4*)(d + i) = o;
}

// ========== GEMM tile core: 128x64 tile, single-buffer gld16 K-loop ==========
template<int EP>
__device__ __forceinline__ void gemm_tile64(
    const bf16_t* __restrict__ A, const bf16_t* __restrict__ W,
    const float* __restrict__ biasA, const float* __restrict__ biasB,
    float* __restrict__ Cf, bf16_t* __restrict__ Cb,
    int N, int K, float scale, int m0, int w_n0, int c_n0,
    bf16_t* As, bf16_t* Bs)
{
    const int tid  = threadIdx.x;
    const int wave = tid >> 6, lane = tid & 63;
    const int wm = wave >> 1, wn = wave & 1;
    const int lrow = lane & 15, quad = lane >> 4;
    const int r8 = lane >> 3, c8 = (lane & 7) << 3;

    f32x4 acc[4][2] = {};

    for (int k0 = 0; k0 < K; k0 += 64) {
        __syncthreads();
#pragma unroll
        for (int j = 0; j < 4; ++j) {
            int base = (wave * 4 + j) * 8;
            gld16(A + (size_t)(m0 + base + r8) * K + k0 + c8, &As[base * 64]);
        }
#pragma unroll
        for (int j = 0; j < 2; ++j) {
            int base = (wave * 2 + j) * 8;
            gld16(W + (size_t)(w_n0 + base + r8) * K + k0 + c8, &Bs[base * 64]);
        }
        __syncthreads();
#pragma unroll
        for (int ks = 0; ks < 2; ++ks) {
            bf16x8 af[4], bfr[2];
#pragma unroll
            for (int mt = 0; mt < 4; ++mt)
                af[mt] = *(const bf16x8*)&As[(wm * 64 + mt * 16 + lrow) * 64 + ks * 32 + quad * 8];
#pragma unroll
            for (int nt = 0; nt < 2; ++nt)
                bfr[nt] = *(const bf16x8*)&Bs[(wn * 32 + nt * 16 + lrow) * 64 + ks * 32 + quad * 8];
#pragma unroll
            for (int mt = 0; mt < 4; ++mt)
#pragma unroll
                for (int nt = 0; nt < 2; ++nt)
                    acc[mt][nt] = __builtin_amdgcn_mfma_f32_16x16x32_bf16(
                        af[mt], bfr[nt], acc[mt][nt], 0, 0, 0);
        }
    }

#pragma unroll
    for (int mt = 0; mt < 4; ++mt) {
#pragma unroll
        for (int nt = 0; nt < 2; ++nt) {
            int nn = wn * 32 + nt * 16 + lrow;
            int col = c_n0 + nn;
            float bvv = (EP == 1 && biasB && col >= 128) ? biasB[col - 128]
                                                         : biasA[col];
#pragma unroll
            for (int r = 0; r < 4; ++r) {
                int row = m0 + wm * 64 + mt * 16 + quad * 4 + r;
                float v = (acc[mt][nt][r] + bvv) * scale;
                if (EP == 0) Cf[(size_t)row * N + col] = v;
                else         Cb[(size_t)row * N + col] = (bf16_t)v;
            }
        }
    }
}

// ---------------- fused Q + K + V projection ----------------
__global__ __launch_bounds__(256) void gemm_qkv(
    const bf16_t* __restrict__ xb, const bf16_t* __restrict__ kvb,
    const bf16_t* __restrict__ Wq, const bf16_t* __restrict__ Wkv,
    const float* __restrict__ bq, const float* __restrict__ bk,
    const float* __restrict__ bv,
    bf16_t* __restrict__ Qb, bf16_t* __restrict__ KVb)
{
    __shared__ __align__(16) bf16_t As[128 * 64];
    __shared__ __align__(16) bf16_t Bs[64 * 64];
    const int m0 = blockIdx.y * 128;
    if (blockIdx.x < 32) {
        int n0 = blockIdx.x * 64;
        gemm_tile64<1>(xb, Wq, bq, nullptr, nullptr, Qb, E_, E_, QSCALE,
                       m0, n0, n0, As, Bs);
    } else {
        int n0 = (blockIdx.x - 32) * 64;
        gemm_tile64<1>(kvb, Wkv, bk, bv, nullptr, KVb, 256, E_, 1.0f,
                       m0, n0, n0, As, Bs);
    }
}

// ---------------- O projection (fp32 out, direct store) ----------------
__global__ __launch_bounds__(256) void gemm_o(
    const bf16_t* __restrict__ A, const bf16_t* __restrict__ W,
    const float* __restrict__ bias, float* __restrict__ Cf)
{
    __shared__ __align__(16) bf16_t As[128 * 64];
    __shared__ __align__(16) bf16_t Bs[64 * 64];
    int n0 = blockIdx.x * 64;
    gemm_tile64<0>(A, W, bias, nullptr, Cf, nullptr, E_, E_, 1.0f,
                   blockIdx.y * 128, n0, n0, As, Bs);
}

// ---------------- flash-style causal MQA attention ----------------
// 8 waves = 4 q-groups (32 rows each) x 2 key-parity waves. Staging period =
// 128 keys; parity wave wk computes key-tile 2p+wk. Per-wave code/registers
// identical to the proven round-2 kernel (116 VGPR, 0 conflicts) -> 4 resident
// waves/SIMD at 2 blocks/CU, per-wave serial chain halved. Partials merged
// once via LDS-overlay epilogue.
// Q pre-scaled bf16 [B,S,H,D]; KV interleaved bf16 [B,S,128K|128V]; O bf16.
__global__ __launch_bounds__(512, 2) void mqa_attn(
    const bf16_t* __restrict__ Q, const bf16_t* __restrict__ KV,
    bf16_t* __restrict__ O)
{
    __shared__ __align__(16) unsigned char SMEM[70656];
    bf16_t (*Kt)[136] = (bf16_t(*)[136])SMEM;            // [k=128][d=128 +pad8]
    bf16_t (*Vt)[136] = (bf16_t(*)[136])(SMEM + 34816);  // [d=128][k=128 +pad8]
    float* rsl = (float*)(SMEM + 69632);                 // [8][32]
    float* mrg = (float*)SMEM;                           // 64 KB overlay for merge

    const int bx = blockIdx.x, h = blockIdx.y, b = blockIdx.z;
    const int qb = b ? bx : (15 - bx);                   // complementary pairing
    const int tid = threadIdx.x, wave = tid >> 6, lane = tid & 63;
    const int wq = wave >> 1, wk = wave & 1;
    const int ln = lane & 31, hi = lane >> 5;
    const int q0w = qb * 128 + wq * 32;

    const bf16_t* kvp = KV + (size_t)(b * S_) * 256;

    // Q fragments (B-operand): lane holds Q[q0w+ln][st*16 + hi*8 + j]
    bf16x8 qf[8];
    {
        const bf16_t* qp = Q + ((size_t)(b * S_ + q0w + ln)) * E_ + h * D_ + hi * 8;
#pragma unroll
        for (int st = 0; st < 8; ++st) qf[st] = *(const bf16x8*)(qp + st * 16);
    }

    f32x16 oacc[4] = {};
    float rs = 0.f;

    const int nper = qb + 1;   // periods of 128 keys (= 2 parity tiles of 64)

    // prefetch regs: 2048 16B-units per period over 512 threads = 4/thread
    bf16x8 kreg[4], vreg[4];
    auto loadKV = [&](int k0) {
#pragma unroll
        for (int i = 0; i < 4; ++i) {
            int c = tid + 512 * i;
            kreg[i] = *(const bf16x8*)(kvp + (size_t)(k0 + (c >> 4)) * 256 + ((c & 15) << 3));
            int n = c & 127, d0 = (c >> 7) << 3;
            vreg[i] = *(const bf16x8*)(kvp + (size_t)(k0 + n) * 256 + 128 + d0);
        }
    };
    loadKV(0);

    for (int p = 0; p < nper; ++p) {
        const int k0 = p * 128;
        __syncthreads();                       // (a) prev compute done, LDS free
#pragma unroll
        for (int i = 0; i < 4; ++i) {
            int c = tid + 512 * i;
            *(bf16x8*)&Kt[c >> 4][(c & 15) << 3] = kreg[i];
            int n = c & 127, d0 = (c >> 7) << 3;
#pragma unroll
            for (int j = 0; j < 8; ++j) Vt[d0 + j][n] = vreg[i][j];
        }
        __syncthreads();                       // (b) staging visible
        if (p + 1 < nper) loadKV(k0 + 128);    // prefetch overlaps compute

        const int k_base = k0 + wk * 64;       // this wave's parity tile
        if (k_base <= q0w + 31) {              // wave-uniform causal skip
            // -------- swapped QK^T: sc[ct] = S^T[k][q=ln] --------
            f32x16 sc[2] = {f32x16{}, f32x16{}};
            __builtin_amdgcn_s_setprio(1);
#pragma unroll
            for (int st = 0; st < 8; ++st) {
                bf16x8 qv = qf[st];
#pragma unroll
                for (int ct = 0; ct < 2; ++ct) {
                    bf16x8 kf = *(const bf16x8*)&Kt[wk * 64 + ct * 32 + ln][st * 16 + hi * 8];
                    sc[ct] = __builtin_amdgcn_mfma_f32_32x32x16_bf16(kf, qv, sc[ct], 0, 0, 0);
                }
            }
            __builtin_amdgcn_s_setprio(0);
            // -------- mask + exp2 softmax (log2-domain scores) --------
            const int qi = q0w + ln;
            const bool diag = (k_base + 63 > q0w);
#pragma unroll
            for (int ct = 0; ct < 2; ++ct) {
#pragma unroll
                for (int r = 0; r < 16; ++r) {
                    float s = sc[ct][r];
                    if (diag) {
                        int kj = k_base + ct * 32 + (r & 3) + 8 * (r >> 2) + 4 * hi;
                        if (kj > qi) s = -1e30f;
                    }
                    float pv = exp2f(fminf(s, 110.f));
                    rs += pv;
                    sc[ct][r] = pv;
                }
            }
            // -------- P -> A-frags in-register (cvt_pk casts + shfl_xor 32) ---
            bf16x8 af[4];
#pragma unroll
            for (int ks = 0; ks < 4; ++ks) {
                const int c = ks >> 1, b8 = (ks & 1) * 8;
                union { bf16_t h[2]; unsigned u; } pk0, pk1, pk2, pk3;
                pk0.h[0] = (bf16_t)sc[c][b8 + 0]; pk0.h[1] = (bf16_t)sc[c][b8 + 1];
                pk1.h[0] = (bf16_t)sc[c][b8 + 2]; pk1.h[1] = (bf16_t)sc[c][b8 + 3];
                pk2.h[0] = (bf16_t)sc[c][b8 + 4]; pk2.h[1] = (bf16_t)sc[c][b8 + 5];
                pk3.h[0] = (bf16_t)sc[c][b8 + 6]; pk3.h[1] = (bf16_t)sc[c][b8 + 7];
                const unsigned U0 = pk0.u, U1 = pk1.u, U2 = pk2.u, U3 = pk3.u;
                const unsigned V0 = __shfl_xor(U0, 32);
                const unsigned V1 = __shfl_xor(U1, 32);
                const unsigned V2 = __shfl_xor(U2, 32);
                const unsigned V3 = __shfl_xor(U3, 32);
                union { unsigned u[4]; bf16x8 v; } W;
                W.u[0] = hi ? V2 : U0;
                W.u[1] = hi ? V3 : U1;
                W.u[2] = hi ? U2 : V0;
                W.u[3] = hi ? U3 : V1;
                af[ks] = W.v;
            }
            // -------- PV: oacc[t] += P * V (B-frag from transposed Vt) --------
            __builtin_amdgcn_s_setprio(1);
#pragma unroll
            for (int ks = 0; ks < 4; ++ks)
#pragma unroll
                for (int t = 0; t < 4; ++t) {
                    bf16x8 vf = *(const bf16x8*)&Vt[t * 32 + ln][wk * 64 + ks * 16 + hi * 8];
                    oacc[t] = __builtin_amdgcn_mfma_f32_32x32x16_bf16(af[ks], vf, oacc[t], 0, 0, 0);
                }
            __builtin_amdgcn_s_setprio(0);
        }
    }

    // -------- epilogue: merge parity partials via LDS, normalize, store ------
    __syncthreads();                           // compute done; LDS reusable
    rs += __shfl_xor(rs, 32);
    if (lane < 32) rsl[wave * 32 + ln] = rs;
    if (wk) {
#pragma unroll
        for (int t = 0; t < 4; ++t) {
            union { f32x16 v; f32x4 q[4]; } u; u.v = oacc[t];
            float* d = mrg + (size_t)(((wq << 2) + t) * 64 + lane) * 16;
#pragma unroll
            for (int r4 = 0; r4 < 4; ++r4) *(f32x4*)(d + r4 * 4) = u.q[r4];
        }
    }
    __syncthreads();
    if (!wk) {
        float inv[16];
#pragma unroll
        for (int r = 0; r < 16; ++r) {
            int ro = (r & 3) + 8 * (r >> 2) + 4 * hi;
            inv[r] = 1.0f / (rsl[(wq * 2) * 32 + ro] + rsl[(wq * 2 + 1) * 32 + ro]);
        }
#pragma unroll
        for (int t = 0; t < 4; ++t) {
            union { f32x16 v; f32x4 q[4]; } u; u.v = oacc[t];
            const float* d = mrg + (size_t)(((wq << 2) + t) * 64 + lane) * 16;
#pragma unroll
            for (int r4 = 0; r4 < 4; ++r4) {
                f32x4 m = *(const f32x4*)(d + r4 * 4);
                u.q[r4] += m;
            }
#pragma unroll
            for (int r = 0; r < 16; ++r) {
                int ro = (r & 3) + 8 * (r >> 2) + 4 * hi;
                O[((size_t)(b * S_ + q0w + ro)) * E_ + h * D_ + t * 32 + ln] =
                    (bf16_t)(u.v[r] * inv[r]);
            }
        }
    }
}

// ---------------- launch ----------------
extern "C" void kernel_launch(void* const* d_in, const int* in_sizes, int n_in,
                              void* d_out, int out_size, void* d_ws, size_t ws_size,
                              hipStream_t stream)
{
    const float* x   = (const float*)d_in[0];
    const float* kv  = (const float*)d_in[1];
    const float* Wq  = (const float*)d_in[2];
    const float* bq  = (const float*)d_in[3];
    const float* Wk  = (const float*)d_in[4];
    const float* bk  = (const float*)d_in[5];
    const float* Wv  = (const float*)d_in[6];
    const float* bv  = (const float*)d_in[7];
    const float* Wo  = (const float*)d_in[8];
    const float* bo  = (const float*)d_in[9];
    float* out = (float*)d_out;

    bf16_t* p    = (bf16_t*)d_ws;
    bf16_t* xb   = p;  p += (size_t)BS_ * E_;
    bf16_t* kvb  = p;  p += (size_t)BS_ * E_;
    bf16_t* Wqb  = p;  p += (size_t)E_ * E_;
    bf16_t* Wkvb = p;  p += (size_t)2 * D_ * E_;
    bf16_t* Wob  = p;  p += (size_t)E_ * E_;
    bf16_t* Qb   = p;  p += (size_t)BS_ * E_;
    bf16_t* KVb  = p;  p += (size_t)BS_ * 256;
    bf16_t* Ob   = p;  p += (size_t)BS_ * E_;

    cvt_all<<<dim3(25088), dim3(256), 0, stream>>>(
        x, kv, Wq, Wk, Wv, Wo,
        xb, kvb, Wqb, Wkvb, Wkvb + (size_t)D_ * E_, Wob);

    gemm_qkv<<<dim3(36, BS_ / 128), 256, 0, stream>>>(
        xb, kvb, Wqb, Wkvb, bq, bk, bv, Qb, KVb);

    mqa_attn<<<dim3(S_ / 128, H_, B_), 512, 0, stream>>>(Qb, KVb, Ob);

    gemm_o<<<dim3(E_ / 64, BS_ / 128), 256, 0, stream>>>(Ob, Wob, bo, out);
}

// Round 6
// 356.619 us; speedup vs baseline: 1.2821x; 1.0868x over previous
//
#include <hip/hip_runtime.h>

#define B_  2
#define S_  2048
#define E_  2048
#define H_  16
#define D_  128
#define BS_ (B_*S_)

typedef __bf16 bf16_t;
typedef __bf16 bf16x8 __attribute__((ext_vector_type(8)));
typedef __bf16 bf16x4 __attribute__((ext_vector_type(4)));
typedef float  f32x4  __attribute__((ext_vector_type(4)));
typedef float  f32x16 __attribute__((ext_vector_type(16)));

// combined softmax scale: 1/sqrt(128) * log2(e), folded into Q projection
#define QSCALE 0.1275174131003543f

// ---------------- async global->LDS, 16B per lane per call ----------------
__device__ __forceinline__ void gld16(const bf16_t* g, bf16_t* l) {
    __builtin_amdgcn_global_load_lds(
        (const __attribute__((address_space(1))) void*)g,
        (__attribute__((address_space(3))) void*)l,
        16, 0, 0);
}

// ---------------- fused fp32 -> bf16 convert (x, kv, 4 weights) ----------------
__global__ void cvt_all(const float* __restrict__ s0, const float* __restrict__ s1,
                        const float* __restrict__ s2, const float* __restrict__ s3,
                        const float* __restrict__ s4, const float* __restrict__ s5,
                        bf16_t* d0, bf16_t* d1, bf16_t* d2,
                        bf16_t* d3, bf16_t* d4, bf16_t* d5)
{
    long i = ((long)blockIdx.x * blockDim.x + threadIdx.x) * 4;
    const float* s; bf16_t* d;
    if      (i <  8388608) { s = s0; d = d0; }
    else if (i < 16777216) { s = s1; d = d1; i -=  8388608; }
    else if (i < 20971520) { s = s2; d = d2; i -= 16777216; }
    else if (i < 21233664) { s = s3; d = d3; i -= 20971520; }
    else if (i < 21495808) { s = s4; d = d4; i -= 21233664; }
    else                   { s = s5; d = d5; i -= 21495808; }
    float4 v = *(const float4*)(s + i);
    bf16x4 o;
    o[0] = (bf16_t)v.x; o[1] = (bf16_t)v.y; o[2] = (bf16_t)v.z; o[3] = (bf16_t)v.w;
    *(bf16x4*)(d + i) = o;
}

// ========== GEMM tile core: 128x64 tile, single-buffer gld16 K-loop ==========
template<int EP>
__device__ __forceinline__ void gemm_tile64(
    const bf16_t* __restrict__ A, const bf16_t* __restrict__ W,
    const float* __restrict__ biasA, const float* __restrict__ biasB,
    float* __restrict__ Cf, bf16_t* __restrict__ Cb,
    int N, int K, float scale, int m0, int w_n0, int c_n0,
    bf16_t* As, bf16_t* Bs)
{
    const int tid  = threadIdx.x;
    const int wave = tid >> 6, lane = tid & 63;
    const int wm = wave >> 1, wn = wave & 1;
    const int lrow = lane & 15, quad = lane >> 4;
    const int r8 = lane >> 3, c8 = (lane & 7) << 3;

    f32x4 acc[4][2] = {};

    for (int k0 = 0; k0 < K; k0 += 64) {
        __syncthreads();
#pragma unroll
        for (int j = 0; j < 4; ++j) {
            int base = (wave * 4 + j) * 8;
            gld16(A + (size_t)(m0 + base + r8) * K + k0 + c8, &As[base * 64]);
        }
#pragma unroll
        for (int j = 0; j < 2; ++j) {
            int base = (wave * 2 + j) * 8;
            gld16(W + (size_t)(w_n0 + base + r8) * K + k0 + c8, &Bs[base * 64]);
        }
        __syncthreads();
#pragma unroll
        for (int ks = 0; ks < 2; ++ks) {
            bf16x8 af[4], bfr[2];
#pragma unroll
            for (int mt = 0; mt < 4; ++mt)
                af[mt] = *(const bf16x8*)&As[(wm * 64 + mt * 16 + lrow) * 64 + ks * 32 + quad * 8];
#pragma unroll
            for (int nt = 0; nt < 2; ++nt)
                bfr[nt] = *(const bf16x8*)&Bs[(wn * 32 + nt * 16 + lrow) * 64 + ks * 32 + quad * 8];
#pragma unroll
            for (int mt = 0; mt < 4; ++mt)
#pragma unroll
                for (int nt = 0; nt < 2; ++nt)
                    acc[mt][nt] = __builtin_amdgcn_mfma_f32_16x16x32_bf16(
                        af[mt], bfr[nt], acc[mt][nt], 0, 0, 0);
        }
    }

#pragma unroll
    for (int mt = 0; mt < 4; ++mt) {
#pragma unroll
        for (int nt = 0; nt < 2; ++nt) {
            int nn = wn * 32 + nt * 16 + lrow;
            int col = c_n0 + nn;
            float bvv = (EP == 1 && biasB && col >= 128) ? biasB[col - 128]
                                                         : biasA[col];
#pragma unroll
            for (int r = 0; r < 4; ++r) {
                int row = m0 + wm * 64 + mt * 16 + quad * 4 + r;
                float v = (acc[mt][nt][r] + bvv) * scale;
                if (EP == 0) Cf[(size_t)row * N + col] = v;
                else         Cb[(size_t)row * N + col] = (bf16_t)v;
            }
        }
    }
}

// ---------------- fused Q + K + V projection ----------------
__global__ __launch_bounds__(256) void gemm_qkv(
    const bf16_t* __restrict__ xb, const bf16_t* __restrict__ kvb,
    const bf16_t* __restrict__ Wq, const bf16_t* __restrict__ Wkv,
    const float* __restrict__ bq, const float* __restrict__ bk,
    const float* __restrict__ bv,
    bf16_t* __restrict__ Qb, bf16_t* __restrict__ KVb)
{
    __shared__ __align__(16) bf16_t As[128 * 64];
    __shared__ __align__(16) bf16_t Bs[64 * 64];
    const int m0 = blockIdx.y * 128;
    if (blockIdx.x < 32) {
        int n0 = blockIdx.x * 64;
        gemm_tile64<1>(xb, Wq, bq, nullptr, nullptr, Qb, E_, E_, QSCALE,
                       m0, n0, n0, As, Bs);
    } else {
        int n0 = (blockIdx.x - 32) * 64;
        gemm_tile64<1>(kvb, Wkv, bk, bv, nullptr, KVb, 256, E_, 1.0f,
                       m0, n0, n0, As, Bs);
    }
}

// ---------------- O projection (fp32 out, direct store) ----------------
__global__ __launch_bounds__(256) void gemm_o(
    const bf16_t* __restrict__ A, const bf16_t* __restrict__ W,
    const float* __restrict__ bias, float* __restrict__ Cf)
{
    __shared__ __align__(16) bf16_t As[128 * 64];
    __shared__ __align__(16) bf16_t Bs[64 * 64];
    int n0 = blockIdx.x * 64;
    gemm_tile64<0>(A, W, bias, nullptr, Cf, nullptr, E_, E_, 1.0f,
                   blockIdx.y * 128, n0, n0, As, Bs);
}

// ---------------- flash-style causal MQA attention ----------------
// Round-2 decomposition (4 waves x 32 q-rows, every wave walks every 64-key
// tile, 2 blocks/CU, complementary pairing) + double-buffered K/V LDS and a
// cross-tile software pipeline: per iter t
//   PV(t-1)[buf^1] -> barrier -> stage(t+1)[buf^1] || QK(t)[buf] || loads(t+2)
//   -> softmax(t) -> af
// One barrier per tile (was 2); staging hides under QK; PV/QK MFMA bursts are
// independent across the barrier; softmax VALU overlaps next iter's MFMAs.
// Q pre-scaled bf16 [B,S,H,D]; KV interleaved bf16 [B,S,128K|128V]; O bf16.
__global__ __launch_bounds__(256, 2) void mqa_attn(
    const bf16_t* __restrict__ Q, const bf16_t* __restrict__ KV,
    bf16_t* __restrict__ O)
{
    __shared__ __align__(16) bf16_t Kt[2][64][136];   // [buf][k][d], pad 8
    __shared__ __align__(16) bf16_t Vt[2][128][72];   // [buf][d][k], pad 8
    __shared__ float rsl[4][32];

    const int bx = blockIdx.x, h = blockIdx.y, b = blockIdx.z;
    const int qb = b ? bx : (15 - bx);                // complementary pairing
    const int tid = threadIdx.x, wave = tid >> 6, lane = tid & 63;
    const int ln = lane & 31, hi = lane >> 5;
    const int q0w = qb * 128 + wave * 32;

    const bf16_t* kvp = KV + (size_t)(b * S_) * 256;

    // Q fragments (B-operand): lane holds Q[q0w+ln][st*16 + hi*8 + j]
    bf16x8 qf[8];
    {
        const bf16_t* qp = Q + ((size_t)(b * S_ + q0w + ln)) * E_ + h * D_ + hi * 8;
#pragma unroll
        for (int st = 0; st < 8; ++st) qf[st] = *(const bf16x8*)(qp + st * 16);
    }

    f32x16 oacc[4] = {};
    bf16x8 af[4] = {};
    float rs0 = 0.f, rs1 = 0.f, rs2 = 0.f, rs3 = 0.f;

    const int NT = 2 * qb + 2;                 // 64-key tiles for this block
    const int Tw = (q0w + 31) >> 6;            // last active tile for this wave

    bf16x8 kreg[4], vreg[4];
    auto loadKV = [&](int kt) {
        const int k0 = kt * 64;
#pragma unroll
        for (int i = 0; i < 4; ++i) {
            int c = tid + 256 * i;
            kreg[i] = *(const bf16x8*)(kvp + (size_t)(k0 + (c >> 4)) * 256 + ((c & 15) << 3));
            int n = c & 63, d0 = (c >> 6) << 3;
            vreg[i] = *(const bf16x8*)(kvp + (size_t)(k0 + n) * 256 + 128 + d0);
        }
    };
    auto stageWrite = [&](int bb) {
#pragma unroll
        for (int i = 0; i < 4; ++i) {
            int c = tid + 256 * i;
            *(bf16x8*)&Kt[bb][c >> 4][(c & 15) << 3] = kreg[i];
            int n = c & 63, d0 = (c >> 6) << 3;
#pragma unroll
            for (int j = 0; j < 8; ++j) Vt[bb][d0 + j][n] = vreg[i][j];
        }
    };
    auto doPV = [&](int vb) {
        __builtin_amdgcn_s_setprio(1);
#pragma unroll
        for (int ks = 0; ks < 4; ++ks)
#pragma unroll
            for (int dt = 0; dt < 4; ++dt) {
                bf16x8 vf = *(const bf16x8*)&Vt[vb][dt * 32 + ln][ks * 16 + hi * 8];
                oacc[dt] = __builtin_amdgcn_mfma_f32_32x32x16_bf16(af[ks], vf, oacc[dt], 0, 0, 0);
            }
        __builtin_amdgcn_s_setprio(0);
    };

    // prologue: tile 0 -> buf0; tile 1 -> regs
    loadKV(0);
    stageWrite(0);
    if (NT > 1) loadKV(1);

    for (int t = 0; t < NT; ++t) {
        const int cur = t & 1;
        if (t >= 1 && t - 1 <= Tw) doPV(cur ^ 1);      // PV of previous tile
        __syncthreads();                               // buf[cur^1] now free; buf[cur] visible
        if (t + 1 < NT) stageWrite(cur ^ 1);           // hides under QK(t)
        if (t + 2 < NT) loadKV(t + 2);
        if (t <= Tw) {
            // -------- swapped QK^T: sc[ct] = S^T[k][q=ln] --------
            f32x16 sc[2] = {f32x16{}, f32x16{}};
            __builtin_amdgcn_s_setprio(1);
#pragma unroll
            for (int st = 0; st < 8; ++st) {
                bf16x8 qv = qf[st];
#pragma unroll
                for (int ct = 0; ct < 2; ++ct) {
                    bf16x8 kf = *(const bf16x8*)&Kt[cur][ct * 32 + ln][st * 16 + hi * 8];
                    sc[ct] = __builtin_amdgcn_mfma_f32_32x32x16_bf16(kf, qv, sc[ct], 0, 0, 0);
                }
            }
            __builtin_amdgcn_s_setprio(0);
            // -------- mask + exp2 softmax (log2-domain scores) --------
            const int k_base = t * 64;
            const int qi = q0w + ln;
            if (k_base + 63 > q0w) {                   // diag tile: masked path
#pragma unroll
                for (int ct = 0; ct < 2; ++ct)
#pragma unroll
                    for (int r = 0; r < 16; ++r) {
                        int kj = k_base + ct * 32 + (r & 3) + 8 * (r >> 2) + 4 * hi;
                        float s = (kj > qi) ? -1e30f : sc[ct][r];
                        float pv = exp2f(fminf(s, 110.f));
                        if ((r & 3) == 0) rs0 += pv;
                        else if ((r & 3) == 1) rs1 += pv;
                        else if ((r & 3) == 2) rs2 += pv;
                        else rs3 += pv;
                        sc[ct][r] = pv;
                    }
            } else {                                   // interior tile: no mask
#pragma unroll
                for (int ct = 0; ct < 2; ++ct)
#pragma unroll
                    for (int r = 0; r < 16; ++r) {
                        float pv = exp2f(fminf(sc[ct][r], 110.f));
                        if ((r & 3) == 0) rs0 += pv;
                        else if ((r & 3) == 1) rs1 += pv;
                        else if ((r & 3) == 2) rs2 += pv;
                        else rs3 += pv;
                        sc[ct][r] = pv;
                    }
            }
            // -------- P -> A-frags in-register (cvt_pk casts + shfl_xor 32) ---
#pragma unroll
            for (int ks = 0; ks < 4; ++ks) {
                const int c = ks >> 1, b8 = (ks & 1) * 8;
                union { bf16_t h[2]; unsigned u; } pk0, pk1, pk2, pk3;
                pk0.h[0] = (bf16_t)sc[c][b8 + 0]; pk0.h[1] = (bf16_t)sc[c][b8 + 1];
                pk1.h[0] = (bf16_t)sc[c][b8 + 2]; pk1.h[1] = (bf16_t)sc[c][b8 + 3];
                pk2.h[0] = (bf16_t)sc[c][b8 + 4]; pk2.h[1] = (bf16_t)sc[c][b8 + 5];
                pk3.h[0] = (bf16_t)sc[c][b8 + 6]; pk3.h[1] = (bf16_t)sc[c][b8 + 7];
                const unsigned U0 = pk0.u, U1 = pk1.u, U2 = pk2.u, U3 = pk3.u;
                const unsigned V0 = __shfl_xor(U0, 32);
                const unsigned V1 = __shfl_xor(U1, 32);
                const unsigned V2 = __shfl_xor(U2, 32);
                const unsigned V3 = __shfl_xor(U3, 32);
                union { unsigned u[4]; bf16x8 v; } W;
                W.u[0] = hi ? V2 : U0;
                W.u[1] = hi ? V3 : U1;
                W.u[2] = hi ? U2 : V0;
                W.u[3] = hi ? U3 : V1;
                af[ks] = W.v;
            }
        }
    }
    if (Tw == NT - 1) doPV(1);                 // drain last tile ((NT-1)&1 == 1)

    // -------- epilogue: full row sums, deferred normalization --------
    float rs = (rs0 + rs1) + (rs2 + rs3);
    rs += __shfl_xor(rs, 32);
    __syncthreads();
    if (lane < 32) rsl[wave][ln] = 1.0f / rs;
    __syncthreads();
#pragma unroll
    for (int dt = 0; dt < 4; ++dt)
#pragma unroll
        for (int r = 0; r < 16; ++r) {
            int ro = (r & 3) + 8 * (r >> 2) + 4 * hi;
            O[((size_t)(b * S_ + q0w + ro)) * E_ + h * D_ + dt * 32 + ln] =
                (bf16_t)(oacc[dt][r] * rsl[wave][ro]);
        }
}

// ---------------- launch ----------------
extern "C" void kernel_launch(void* const* d_in, const int* in_sizes, int n_in,
                              void* d_out, int out_size, void* d_ws, size_t ws_size,
                              hipStream_t stream)
{
    const float* x   = (const float*)d_in[0];
    const float* kv  = (const float*)d_in[1];
    const float* Wq  = (const float*)d_in[2];
    const float* bq  = (const float*)d_in[3];
    const float* Wk  = (const float*)d_in[4];
    const float* bk  = (const float*)d_in[5];
    const float* Wv  = (const float*)d_in[6];
    const float* bv  = (const float*)d_in[7];
    const float* Wo  = (const float*)d_in[8];
    const float* bo  = (const float*)d_in[9];
    float* out = (float*)d_out;

    bf16_t* p    = (bf16_t*)d_ws;
    bf16_t* xb   = p;  p += (size_t)BS_ * E_;
    bf16_t* kvb  = p;  p += (size_t)BS_ * E_;
    bf16_t* Wqb  = p;  p += (size_t)E_ * E_;
    bf16_t* Wkvb = p;  p += (size_t)2 * D_ * E_;
    bf16_t* Wob  = p;  p += (size_t)E_ * E_;
    bf16_t* Qb   = p;  p += (size_t)BS_ * E_;
    bf16_t* KVb  = p;  p += (size_t)BS_ * 256;
    bf16_t* Ob   = p;  p += (size_t)BS_ * E_;

    cvt_all<<<dim3(25088), dim3(256), 0, stream>>>(
        x, kv, Wq, Wk, Wv, Wo,
        xb, kvb, Wqb, Wkvb, Wkvb + (size_t)D_ * E_, Wob);

    gemm_qkv<<<dim3(36, BS_ / 128), 256, 0, stream>>>(
        xb, kvb, Wqb, Wkvb, bq, bk, bv, Qb, KVb);

    mqa_attn<<<dim3(S_ / 128, H_, B_), 256, 0, stream>>>(Qb, KVb, Ob);

    gemm_o<<<dim3(E_ / 64, BS_ / 128), 256, 0, stream>>>(Ob, Wob, bo, out);
}